// Round 1
// baseline (1847.916 us; speedup 1.0000x reference)
//
#include <hip/hip_runtime.h>

#define NN 100000
#define NE 1600000
#define DD 64
#define HID 128

typedef const __attribute__((address_space(1))) unsigned int* gas1_t;
typedef __attribute__((address_space(3)))       unsigned int* las3_t;

// Region-pin: force all 64 floats into live VGPRs at this program point.
// Must be re-executed INSIDE the hot loop: a single pre-loop pin only fixes
// the values at one point and the allocator then spills them (Round-0
// evidence: VGPR_Count=40 < 64 pinned floats).
__device__ __forceinline__ void pin64(float (&w)[DD]) {
    #pragma unroll
    for (int k = 0; k < DD; k += 8)
        asm volatile("" : "+v"(w[k+0]), "+v"(w[k+1]), "+v"(w[k+2]), "+v"(w[k+3]),
                          "+v"(w[k+4]), "+v"(w[k+5]), "+v"(w[k+6]), "+v"(w[k+7]));
}

__device__ __forceinline__ void load_row64(float (&w)[DD], const float* __restrict__ src) {
    const float4* s4 = reinterpret_cast<const float4*>(src);
    #pragma unroll
    for (int q = 0; q < DD / 4; ++q) {
        float4 v = s4[q];
        w[4*q+0] = v.x; w[4*q+1] = v.y; w[4*q+2] = v.z; w[4*q+3] = v.w;
    }
}

// ---------------------------------------------------------------------------
// Edge kernel: block = 4 waves, tile = 64 edges (16/wave).
//  - edge_attr tiles: HBM -> LDS via global_load_lds x16B, double-buffered;
//    per-edge row read back as uniform-address ds_read_b128 (broadcast,
//    conflict-free). Replaces the per-edge s_load + lgkmcnt(0) serial chain.
//  - lin_w row `lane` pinned in 64 VGPRs, re-pinned every tile (region pin).
//  - __syncthreads() provides the vmcnt(0) drain for the staged loads.
// ---------------------------------------------------------------------------
#define ETILE 64

__global__ __launch_bounds__(256, 4)
void edge_kernel(const float* __restrict__ edge_attr,
                 const int*   __restrict__ edge_index,
                 const float* __restrict__ x,
                 const float* __restrict__ lin_w,
                 const float* __restrict__ lin_b,
                 float* agg)
{
    __shared__ float ea[2][ETILE * DD];          // 2 x 16 KB double buffer

    const int lane = threadIdx.x & 63;
    const int wvu  = __builtin_amdgcn_readfirstlane(threadIdx.x >> 6);

    float w[DD];
    load_row64(w, lin_w + lane * DD);
    const float bj = lin_b[lane];

    const int ntiles = NE / ETILE;               // 25000
    const int tstep  = gridDim.x;
    int t = blockIdx.x;

    // Prologue: stage tile t into buffer 0.
    {
        const float* g = edge_attr + (size_t)t * (ETILE * DD);
        #pragma unroll
        for (int c = 0; c < 4; ++c) {
            const int off = c * 1024 + wvu * 256;            // floats
            __builtin_amdgcn_global_load_lds((gas1_t)(g + off + lane * 4),
                                             (las3_t)(&ea[0][off]), 16, 0, 0);
        }
    }
    __syncthreads();                              // implicit vmcnt(0) drain

    int cur = 0;
    for (; t < ntiles; t += tstep) {
        // Issue next tile's staging before compute (overlaps with FMAs).
        const int tn = t + tstep;
        if (tn < ntiles) {
            const float* g = edge_attr + (size_t)tn * (ETILE * DD);
            #pragma unroll
            for (int c = 0; c < 4; ++c) {
                const int off = c * 1024 + wvu * 256;
                __builtin_amdgcn_global_load_lds((gas1_t)(g + off + lane * 4),
                                                 (las3_t)(&ea[cur ^ 1][off]), 16, 0, 0);
            }
        }

        pin64(w);                                 // region pin, once per tile

        const int ebase = t * ETILE + wvu * 16;
        for (int i = 0; i < 16; ++i) {
            const int eg  = ebase + i;
            const int src = edge_index[eg];       // s_load, K$-line reused x16
            const int dst = edge_index[NE + eg];  // s_load
            float xv = x[(size_t)src * DD + lane];           // coalesced gather

            const float4* ev =
                reinterpret_cast<const float4*>(&ea[cur][(wvu * 16 + i) * DD]);
            float a0 = 0.f, a1 = 0.f, a2 = 0.f, a3 = 0.f;
            #pragma unroll
            for (int q = 0; q < 16; ++q) {        // MUST unroll: w[] static idx
                float4 e4 = ev[q];                // ds_read_b128 broadcast
                a0 = fmaf(e4.x, w[4*q+0], a0);
                a1 = fmaf(e4.y, w[4*q+1], a1);
                a2 = fmaf(e4.z, w[4*q+2], a2);
                a3 = fmaf(e4.w, w[4*q+3], a3);
            }
            float m = xv + bj + ((a0 + a1) + (a2 + a3));
            m = m > 0.0f ? m : 0.0f;
            unsafeAtomicAdd(&agg[(size_t)dst * DD + lane], m);
        }
        __syncthreads();                          // drain stage loads + barrier
        cur ^= 1;
    }
}

// ---------------------------------------------------------------------------
// Node MLP: block = 4 waves, tile = 64 nodes (16/wave), 4 passes so no lane
// ever needs more than 64 weight VGPRs:
//   stage h-tile -> LDS (coalesced, vector path)
//   pass A: h1[0:64]   = relu(W0[0:64]  h + b0)   (W0 row `lane` in regs)
//   pass B: h1[64:128] = relu(W0[64:128]h + b0)   (reload regs)
//   pass C: acc = b1 + W1[:,0:64]  h1[0:64]       (W1 row cols 0:64 in regs)
//   pass D: out = acc + W1[:,64:128] h1[64:128]
// h and h1 are read as uniform-address ds_read_b128 broadcasts — no scalar
// path, no per-node lgkmcnt(0) round trips.
// ---------------------------------------------------------------------------
#define MT 64

__global__ __launch_bounds__(256, 3)
void mlp_kernel(const float* __restrict__ h_in,
                float* __restrict__ out,
                const float* __restrict__ w0, const float* __restrict__ b0,
                const float* __restrict__ w1, const float* __restrict__ b1)
{
    __shared__ float hls[MT * DD];                // 16 KB
    __shared__ float h1s[MT * HID];               // 32 KB

    const int lane = threadIdx.x & 63;
    const int wvu  = __builtin_amdgcn_readfirstlane(threadIdx.x >> 6);
    const int nb   = blockIdx.x * MT;             // first node of this tile

    const float b0a = b0[lane], b0b = b0[lane + 64], b1j = b1[lane];

    // Stage h tile (tail tile guarded per-lane; masked lanes skip the load).
    #pragma unroll
    for (int c = 0; c < 4; ++c) {
        const int off = c * 1024 + wvu * 256;
        if (nb * DD + off + lane * 4 < NN * DD)
            __builtin_amdgcn_global_load_lds((gas1_t)(h_in + (size_t)nb * DD + off + lane * 4),
                                             (las3_t)(&hls[off]), 16, 0, 0);
    }
    __syncthreads();                              // cross-wave staging

    float w[DD];
    float acc2[16];

    // ---- layer 1, half A: h1 rows 0..63 ----
    load_row64(w, w0 + lane * DD);
    pin64(w);
    for (int nl = 0; nl < 16; ++nl) {
        const int node = wvu * 16 + nl;
        const float4* hv = reinterpret_cast<const float4*>(&hls[node * DD]);
        float a0 = b0a, a1 = 0.f, a2 = 0.f, a3 = 0.f;
        #pragma unroll
        for (int q = 0; q < 16; ++q) {
            float4 h4 = hv[q];
            a0 = fmaf(h4.x, w[4*q+0], a0);
            a1 = fmaf(h4.y, w[4*q+1], a1);
            a2 = fmaf(h4.z, w[4*q+2], a2);
            a3 = fmaf(h4.w, w[4*q+3], a3);
        }
        float v = (a0 + a1) + (a2 + a3);
        h1s[node * HID + lane] = v > 0.0f ? v : 0.0f;
    }

    // ---- layer 1, half B: h1 rows 64..127 ----
    load_row64(w, w0 + (lane + 64) * DD);
    pin64(w);
    for (int nl = 0; nl < 16; ++nl) {
        const int node = wvu * 16 + nl;
        const float4* hv = reinterpret_cast<const float4*>(&hls[node * DD]);
        float a0 = b0b, a1 = 0.f, a2 = 0.f, a3 = 0.f;
        #pragma unroll
        for (int q = 0; q < 16; ++q) {
            float4 h4 = hv[q];
            a0 = fmaf(h4.x, w[4*q+0], a0);
            a1 = fmaf(h4.y, w[4*q+1], a1);
            a2 = fmaf(h4.z, w[4*q+2], a2);
            a3 = fmaf(h4.w, w[4*q+3], a3);
        }
        float v = (a0 + a1) + (a2 + a3);
        h1s[node * HID + 64 + lane] = v > 0.0f ? v : 0.0f;
    }
    // No barrier: each wave wrote/reads only its own 16 nodes' h1 rows.

    // ---- layer 2, k = 0..63 ----
    load_row64(w, w1 + lane * HID);
    pin64(w);
    #pragma unroll                                 // static acc2[] indexing
    for (int nl = 0; nl < 16; ++nl) {
        const int node = wvu * 16 + nl;
        const float4* pv = reinterpret_cast<const float4*>(&h1s[node * HID]);
        float a0 = b1j, a1 = 0.f, a2 = 0.f, a3 = 0.f;
        #pragma unroll
        for (int q = 0; q < 16; ++q) {
            float4 p4 = pv[q];
            a0 = fmaf(p4.x, w[4*q+0], a0);
            a1 = fmaf(p4.y, w[4*q+1], a1);
            a2 = fmaf(p4.z, w[4*q+2], a2);
            a3 = fmaf(p4.w, w[4*q+3], a3);
        }
        acc2[nl] = (a0 + a1) + (a2 + a3);
    }

    // ---- layer 2, k = 64..127 + store ----
    load_row64(w, w1 + lane * HID + 64);
    pin64(w);
    #pragma unroll
    for (int nl = 0; nl < 16; ++nl) {
        const int node = wvu * 16 + nl;
        const float4* pv = reinterpret_cast<const float4*>(&h1s[node * HID + 64]);
        float a0 = 0.f, a1 = 0.f, a2 = 0.f, a3 = 0.f;
        #pragma unroll
        for (int q = 0; q < 16; ++q) {
            float4 p4 = pv[q];
            a0 = fmaf(p4.x, w[4*q+0], a0);
            a1 = fmaf(p4.y, w[4*q+1], a1);
            a2 = fmaf(p4.z, w[4*q+2], a2);
            a3 = fmaf(p4.w, w[4*q+3], a3);
        }
        const int gn = nb + node;
        if (gn < NN)
            out[(size_t)gn * DD + lane] = acc2[nl] + ((a0 + a1) + (a2 + a3));
    }
}

extern "C" void kernel_launch(void* const* d_in, const int* in_sizes, int n_in,
                              void* d_out, int out_size, void* d_ws, size_t ws_size,
                              hipStream_t stream) {
    const float* x          = (const float*)d_in[0];
    const int*   edge_index = (const int*)  d_in[1];
    const float* edge_attr  = (const float*)d_in[2];
    const float* lin_w      = (const float*)d_in[3];
    const float* lin_b      = (const float*)d_in[4];
    const float* w0         = (const float*)d_in[5];
    const float* b0         = (const float*)d_in[6];
    const float* w1         = (const float*)d_in[7];
    const float* b1         = (const float*)d_in[8];
    float* out = (float*)d_out;

    const size_t hbytes = (size_t)NN * DD * sizeof(float);
    float* hbuf = (ws_size >= hbytes) ? (float*)d_ws : out;

    // h starts as x (EPS=0: h = (1+eps)*x + agg).
    hipMemcpyAsync(hbuf, x, hbytes, hipMemcpyDeviceToDevice, stream);

    edge_kernel<<<2048, 256, 0, stream>>>(edge_attr, edge_index, x,
                                          lin_w, lin_b, hbuf);
    mlp_kernel<<<(NN + MT - 1) / MT, 256, 0, stream>>>(hbuf, out, w0, b0, w1, b1);
}